// Round 16
// baseline (150.888 us; speedup 1.0000x reference)
//
#include <hip/hip_runtime.h>
#include <math.h>

#define B_N    32768
#define D_N    128
#define HIST_N 30
#define M_N    15
#define H_N    4

#define TILE_ROWS   512
#define TILE_FLOATS (TILE_ROWS * HIST_N)          // 15360 floats = 61440 B
#define TILE_F4     (TILE_FLOATS / 4)             // 3840 float4
#define WAVE_ROWS   32                            // rows staged+computed per wave
#define WAVE_F4     240                           // 32 rows = 240 f4 = 3840 B
#define WAVE_FLOATS (WAVE_F4 * 4)                 // 960 floats
#define NBLOCKS     256                           // 1 block/CU, one stream per CU
#define NTHREADS    1024                          // 16 waves/CU (r16 lever: 8 -> 16)
#define TPB         (B_N * D_N / TILE_ROWS / NBLOCKS)   // 32 contiguous tiles

typedef float f32x4 __attribute__((ext_vector_type(4)));

// ---------------------------------------------------------------------------
// Fused persistent kernel, register-staged, wave-private pipeline, NT loads.
// r16 single-variable change vs r15: 1024-thread block -> 16 waves/CU (still
// one contiguous per-CU stream). Each wave owns 32 rows/tile: 4 NT loads
// (3 full + lanes<48), 4 ds_writes, lanes<32 compute. HW forces VGPR<=128;
// live set ~120 (sets now 4xf32x4). Spill detection: WRITE_SIZE >> 18MB.
// Trajectory: 119.4 -> 112.5 (NT) -> 109.3 (8 waves). TLP is the only lever
// still moving the number; this is the last available doubling.
//   vmcnt ladder (4 loads/tile): k==0 -> 4; steady -> 5; last -> 0.
// ---------------------------------------------------------------------------
__global__ __launch_bounds__(NTHREADS, 1) void fused_kernel(
        const float* __restrict__ pa,
        const float* __restrict__ w1,
        const float* __restrict__ b1,
        const float* __restrict__ b2,
        const float* __restrict__ b3,
        const float* __restrict__ cw,
        const float* __restrict__ ss,
        const float* __restrict__ sh,
        const float* __restrict__ al,
        const float* __restrict__ rs,
        float* __restrict__ out) {
    const int tid   = threadIdx.x;
    const int lane  = tid & 63;
    const int wv_id = tid >> 6;                 // wave 0..15
    const int row_g = wv_id * WAVE_ROWS + (lane & (WAVE_ROWS - 1)); // 0..511
    const int d     = row_g & (D_N - 1);

    __shared__ __align__(16) f32x4 lds4[2][TILE_F4];      // 2 x 61440 B
    __shared__ float W1c[H_N][D_N];                       // 2 KB
    __shared__ float Gsh[16];
    __shared__ float Msh[32];                             // M2[16], M3[16]

    const f32x4* pa4 = (const f32x4*)pa;
    const size_t tile0 = (size_t)blockIdx.x * TPB;        // contiguous chunk

#define LOAD_SET(v0,v1,v2,v3,t) do {                                      \
        const f32x4* s_ = pa4 + (size_t)(t) * TILE_F4 + wv_id * WAVE_F4;  \
        v0 = __builtin_nontemporal_load(s_ + lane);                       \
        v1 = __builtin_nontemporal_load(s_ + 64 + lane);                  \
        v2 = __builtin_nontemporal_load(s_ + 128 + lane);                 \
        if (lane < 48) v3 = __builtin_nontemporal_load(s_ + 192 + lane);  \
    } while (0)

#define WRITE_SET(v0,v1,v2,v3,buf) do {                                \
        f32x4* L_ = &lds4[buf][0] + wv_id * WAVE_F4;                   \
        L_[lane] = v0;        L_[64 + lane] = v1;                      \
        L_[128 + lane] = v2;                                           \
        if (lane < 48) L_[192 + lane] = v3;                            \
    } while (0)

    f32x4 a0, a1, a2, a3;
    f32x4 b0, b1r, b2r, b3r;
    a3 = (f32x4){0.f, 0.f, 0.f, 0.f};
    b3r = (f32x4){0.f, 0.f, 0.f, 0.f};

    // prologue: tiles 0 and 1 in flight before anything else
    LOAD_SET(a0, a1, a2, a3, tile0);
    LOAD_SET(b0, b1r, b2r, b3r, tile0 + 1);

    // ---- per-d parameter loads (overlap the prologue loads) ----
    float wv[M_N][H_N];
#pragma unroll
    for (int m = 0; m < M_N; ++m)
#pragma unroll
        for (int h = 0; h < H_N; ++h)
            wv[m][h] = w1[(m * H_N + h) * D_N + d];

    float b1v[H_N], b2v[H_N];
#pragma unroll
    for (int h = 0; h < H_N; ++h) {
        b1v[h] = b1[h * D_N + d];
        b2v[h] = b2[h * D_N + d];
    }
    const float b3v = b3[d];

    // ---- softmax(cw), redundant per-thread ----
    float swm[M_N];
    {
        float mx = cw[0];
#pragma unroll
        for (int m = 1; m < M_N; ++m) mx = fmaxf(mx, cw[m]);
        float s = 0.f;
#pragma unroll
        for (int m = 0; m < M_N; ++m) { swm[m] = expf(cw[m] - mx); s += swm[m]; }
        float inv = 1.f / s;
#pragma unroll
        for (int m = 0; m < M_N; ++m) swm[m] *= inv;
    }

    // ---- W1c into LDS ----
    if (tid < 128) {
#pragma unroll
        for (int h = 0; h < H_N; ++h) {
            float acc = 0.f;
#pragma unroll
            for (int m = 0; m < M_N; ++m)
                acc = fmaf(swm[m], w1[(m * H_N + h) * D_N + tid], acc);
            W1c[h][tid] = acc;
        }
    }
    asm volatile("s_waitcnt lgkmcnt(0)" ::: "memory");
    __builtin_amdgcn_s_barrier();

    // ---- Gram (16 threads, staggered) ----
    if (tid < 16) {
        const int i = tid >> 2, j = tid & 3;
        float s = 0.f;
        for (int st = 0; st < 128; ++st) {
            int dd = (st + tid * 8) & 127;
            s = fmaf(W1c[i][dd], W1c[j][dd], s);
        }
        Gsh[tid] = s;
    }
    asm volatile("s_waitcnt lgkmcnt(0)" ::: "memory");
    __builtin_amdgcn_s_barrier();

    // ---- thread 0: Jacobi + two-stage spectral scalars -> M2, M3 ----
    if (tid == 0) {
        float G[4][4], U[4][4];
#pragma unroll
        for (int i = 0; i < 4; ++i)
#pragma unroll
            for (int j = 0; j < 4; ++j) {
                G[i][j] = Gsh[i * 4 + j];
                U[i][j] = (i == j) ? 1.f : 0.f;
            }
        for (int sweep = 0; sweep < 6; ++sweep)
            for (int p = 0; p < 3; ++p)
                for (int q = p + 1; q < 4; ++q) {
                    float apq = G[p][q];
                    if (fabsf(apq) < 1e-30f) continue;
                    float theta = (G[q][q] - G[p][p]) / (2.f * apq);
                    float t = ((theta >= 0.f) ? 1.f : -1.f) /
                              (fabsf(theta) + sqrtf(theta * theta + 1.f));
                    float c = 1.f / sqrtf(t * t + 1.f), sn = t * c;
                    for (int i = 0; i < 4; ++i) {
                        float gip = G[i][p], giq = G[i][q];
                        G[i][p] = c * gip - sn * giq;
                        G[i][q] = sn * gip + c * giq;
                    }
                    for (int i = 0; i < 4; ++i) {
                        float gpi = G[p][i], gqi = G[q][i];
                        G[p][i] = c * gpi - sn * gqi;
                        G[q][i] = sn * gpi + c * gqi;
                    }
                    for (int i = 0; i < 4; ++i) {
                        float uip = U[i][p], uiq = U[i][q];
                        U[i][p] = c * uip - sn * uiq;
                        U[i][q] = sn * uip + c * uiq;
                    }
                }
        float lam[4];
#pragma unroll
        for (int i = 0; i < 4; ++i) lam[i] = G[i][i];
        int ord[4] = {0, 1, 2, 3};
        for (int i = 0; i < 4; ++i)
            for (int j = i + 1; j < 4; ++j)
                if (lam[ord[j]] > lam[ord[i]]) { int t2 = ord[i]; ord[i] = ord[j]; ord[j] = t2; }

        const float a = al[0], r = rs[0];
        float c1[4], S2a[4];
        for (int p = 0; p < 4; ++p) {
            int e = ord[p];
            float S = sqrtf(fmaxf(lam[e], 0.f));
            float x = ss[p];
            float sp = (x > 20.f) ? x : log1pf(expf(x));
            float ratio = (S > 1e-30f) ? ((sp * S + sh[p]) / S) : sp;
            c1[e] = a * ratio + r;
            S2a[e] = fabsf(c1[e]) * S;      // |singular values| of W2
        }
        int ord2[4] = {0, 1, 2, 3};
        for (int i = 0; i < 4; ++i)
            for (int j = i + 1; j < 4; ++j)
                if (S2a[ord2[j]] > S2a[ord2[i]]) { int t2 = ord2[i]; ord2[i] = ord2[j]; ord2[j] = t2; }
        float c12[4];
        for (int p = 0; p < 4; ++p) {
            int e = ord2[p];
            float Sa = S2a[e];
            float x = ss[p];
            float sp = (x > 20.f) ? x : log1pf(expf(x));
            float ratio2 = (Sa > 1e-30f) ? ((sp * Sa + sh[p]) / Sa) : sp;
            c12[e] = (a * ratio2 + r) * c1[e];
        }
#pragma unroll
        for (int i = 0; i < 4; ++i)
#pragma unroll
            for (int j = 0; j < 4; ++j) {
                float m2 = 0.f, m3 = 0.f;
#pragma unroll
                for (int e = 0; e < 4; ++e) {
                    float uu = U[i][e] * U[j][e];
                    m2 = fmaf(uu, c1[e], m2);
                    m3 = fmaf(uu, c12[e], m3);
                }
                Msh[i * 4 + j] = m2;
                Msh[16 + i * 4 + j] = m3;
            }
    }
    asm volatile("s_waitcnt lgkmcnt(0)" ::: "memory");
    __builtin_amdgcn_s_barrier();

    // ---- per-thread W2/W3 columns ----
    float w2v[H_N], w3v[H_N];
#pragma unroll
    for (int h = 0; h < H_N; ++h) {
        float s2 = 0.f, s3 = 0.f;
#pragma unroll
        for (int k4 = 0; k4 < 4; ++k4) {
            float wc = W1c[k4][d];
            s2 = fmaf(Msh[h * 4 + k4], wc, s2);
            s3 = fmaf(Msh[16 + h * 4 + k4], wc, s3);
        }
        w2v[h] = s2;
        w3v[h] = s3;
    }

    const bool active = (lane < WAVE_ROWS);
    // thread's LDS row base (floats): wave region + row*30 + 15
    const int rd_base = wv_id * WAVE_FLOATS + (lane & (WAVE_ROWS - 1)) * HIST_N
                      + (HIST_N - M_N);

    auto compute_tile = [&](int buf, size_t t) {
        if (active) {
            const float* L = (const float*)&lds4[buf][0] + rd_base;
            float x0 = L[0];
            float h1[H_N];
#pragma unroll
            for (int h = 0; h < H_N; ++h) h1[h] = x0 * wv[0][h];
#pragma unroll
            for (int c = 0; c < 7; ++c) {
                float2 q = *(const float2*)(L + 1 + 2 * c);   // 8B-aligned
#pragma unroll
                for (int h = 0; h < H_N; ++h) h1[h] = fmaf(q.x, wv[1 + 2 * c][h], h1[h]);
#pragma unroll
                for (int h = 0; h < H_N; ++h) h1[h] = fmaf(q.y, wv[2 + 2 * c][h], h1[h]);
            }
            float acc = b3v;
#pragma unroll
            for (int h = 0; h < H_N; ++h) {
                float v = fmaxf(h1[h] + b1v[h], 0.f);
                float u = fmaxf(fmaf(v, w2v[h], b2v[h]), 0.f);
                acc = fmaf(u, w3v[h], acc);
            }
            out[t * TILE_ROWS + row_g] = acc;
        }
    };

    // ---- main loop: wave-private, no barriers, counted vmcnt ----
    for (int k = 0; k < TPB; k += 2) {
        // tile k: set A -> buf0
        if (k == 0) asm volatile("s_waitcnt vmcnt(4)" ::: "memory");
        else        asm volatile("s_waitcnt vmcnt(5)" ::: "memory");
        WRITE_SET(a0, a1, a2, a3, 0);
        asm volatile("s_waitcnt lgkmcnt(0)" ::: "memory");
        compute_tile(0, tile0 + k);
        if (k + 2 < TPB) LOAD_SET(a0, a1, a2, a3, tile0 + k + 2);

        // tile k+1: set B -> buf1
        if (k + 1 == TPB - 1) asm volatile("s_waitcnt vmcnt(0)" ::: "memory");
        else                  asm volatile("s_waitcnt vmcnt(5)" ::: "memory");
        WRITE_SET(b0, b1r, b2r, b3r, 1);
        asm volatile("s_waitcnt lgkmcnt(0)" ::: "memory");
        compute_tile(1, tile0 + k + 1);
        if (k + 3 < TPB) LOAD_SET(b0, b1r, b2r, b3r, tile0 + k + 3);
    }
#undef LOAD_SET
#undef WRITE_SET
}

extern "C" void kernel_launch(void* const* d_in, const int* in_sizes, int n_in,
                              void* d_out, int out_size, void* d_ws, size_t ws_size,
                              hipStream_t stream) {
    const float* pa = (const float*)d_in[0];   // (B, D, HIST)
    const float* w1 = (const float*)d_in[1];   // (M, H, D)
    const float* b1 = (const float*)d_in[2];   // (1, H, D)
    const float* b2 = (const float*)d_in[3];   // (1, H, D)
    const float* b3 = (const float*)d_in[4];   // (1, D)
    const float* cw = (const float*)d_in[5];   // (M,)
    const float* ss = (const float*)d_in[6];   // (RANK,)
    const float* sh = (const float*)d_in[7];   // (RANK,)
    const float* al = (const float*)d_in[8];   // (1,)
    const float* rs = (const float*)d_in[9];   // (1,)
    float* out = (float*)d_out;                // (B, D) f32

    fused_kernel<<<NBLOCKS, NTHREADS, 0, stream>>>(pa, w1, b1, b2, b3, cw, ss, sh, al, rs, out);
}

// Round 17
// 109.520 us; speedup vs baseline: 1.3777x; 1.3777x over previous
//
#include <hip/hip_runtime.h>
#include <math.h>

#define B_N    32768
#define D_N    128
#define HIST_N 30
#define M_N    15
#define H_N    4

#define TILE_ROWS   512
#define TILE_FLOATS (TILE_ROWS * HIST_N)          // 15360 floats = 61440 B
#define TILE_F4     (TILE_FLOATS / 4)             // 3840 float4
#define WAVE_F4     480                           // per-wave: 64 rows = 480 f4
#define WAVE_FLOATS (WAVE_F4 * 4)                 // 1920 floats
#define NBLOCKS     256                           // 1 block/CU, one stream per CU
#define NTHREADS    512                           // 8 waves/CU
#define TPB         (B_N * D_N / TILE_ROWS / NBLOCKS)   // 32 contiguous tiles

typedef float f32x4 __attribute__((ext_vector_type(4)));

// ---------------------------------------------------------------------------
// FINAL (r15 revert): fused persistent kernel, register-staged, wave-private
// pipeline, non-temporal loads. 109.3us = best of 16 rounds.
// Lever history: NT loads -6% (r14); 4->8 waves -3% (r15); 16 waves spills
// (r16, VGPR cap 128 < ~130 live set); depth-3 null (r10); DMA path == reg
// path pre-NT (r5/r12); stream contiguity -3% (r13). Remaining gap to the
// 83us traffic floor: serial param prologue + HBM read-vs-write asymmetry
// observed in every config (fills 6.8-7.1 TB/s vs reads ~4.8 TB/s).
//   iter k (even->set A/buf0, odd->set B/buf1), per wave:
//     vmcnt(k==0?8 : k==last?0 : 9)   // drain tile k's 8 loads only
//     ds_write set -> buf ; lgkmcnt(0)
//     compute own 64 rows from buf ; store out
//     issue NT loads T_{k+2} into the just-freed set
// ---------------------------------------------------------------------------
__global__ __launch_bounds__(NTHREADS, 1) void fused_kernel(
        const float* __restrict__ pa,
        const float* __restrict__ w1,
        const float* __restrict__ b1,
        const float* __restrict__ b2,
        const float* __restrict__ b3,
        const float* __restrict__ cw,
        const float* __restrict__ ss,
        const float* __restrict__ sh,
        const float* __restrict__ al,
        const float* __restrict__ rs,
        float* __restrict__ out) {
    const int tid   = threadIdx.x;
    const int lane  = tid & 63;
    const int wv_id = tid >> 6;                 // wave 0..7
    const int d     = tid & 127;

    __shared__ __align__(16) f32x4 lds4[2][TILE_F4];      // 2 x 61440 B
    __shared__ float W1c[H_N][D_N];                       // 2 KB
    __shared__ float Gsh[16];
    __shared__ float Msh[32];                             // M2[16], M3[16]

    const f32x4* pa4 = (const f32x4*)pa;
    const size_t tile0 = (size_t)blockIdx.x * TPB;        // contiguous chunk

#define LOAD_SET(v0,v1,v2,v3,v4,v5,v6,v7,t) do {                          \
        const f32x4* s_ = pa4 + (size_t)(t) * TILE_F4 + wv_id * WAVE_F4;  \
        v0 = __builtin_nontemporal_load(s_ + lane);                       \
        v1 = __builtin_nontemporal_load(s_ + 64 + lane);                  \
        v2 = __builtin_nontemporal_load(s_ + 128 + lane);                 \
        v3 = __builtin_nontemporal_load(s_ + 192 + lane);                 \
        v4 = __builtin_nontemporal_load(s_ + 256 + lane);                 \
        v5 = __builtin_nontemporal_load(s_ + 320 + lane);                 \
        v6 = __builtin_nontemporal_load(s_ + 384 + lane);                 \
        if (lane < 32) v7 = __builtin_nontemporal_load(s_ + 448 + lane);  \
    } while (0)

#define WRITE_SET(v0,v1,v2,v3,v4,v5,v6,v7,buf) do {                    \
        f32x4* L_ = &lds4[buf][0] + wv_id * WAVE_F4;                   \
        L_[lane] = v0;        L_[64 + lane] = v1;                      \
        L_[128 + lane] = v2;  L_[192 + lane] = v3;                     \
        L_[256 + lane] = v4;  L_[320 + lane] = v5;                     \
        L_[384 + lane] = v6;                                           \
        if (lane < 32) L_[448 + lane] = v7;                            \
    } while (0)

    f32x4 a0, a1, a2, a3, a4, a5, a6, a7;
    f32x4 b0, b1r, b2r, b3r, b4, b5, b6, b7;
    a7 = (f32x4){0.f, 0.f, 0.f, 0.f};
    b7 = (f32x4){0.f, 0.f, 0.f, 0.f};

    // prologue: tiles 0 and 1 in flight before anything else
    LOAD_SET(a0, a1, a2, a3, a4, a5, a6, a7, tile0);
    LOAD_SET(b0, b1r, b2r, b3r, b4, b5, b6, b7, tile0 + 1);

    // ---- per-d parameter loads (overlap the prologue loads) ----
    float wv[M_N][H_N];
#pragma unroll
    for (int m = 0; m < M_N; ++m)
#pragma unroll
        for (int h = 0; h < H_N; ++h)
            wv[m][h] = w1[(m * H_N + h) * D_N + d];

    float b1v[H_N], b2v[H_N];
#pragma unroll
    for (int h = 0; h < H_N; ++h) {
        b1v[h] = b1[h * D_N + d];
        b2v[h] = b2[h * D_N + d];
    }
    const float b3v = b3[d];

    // ---- softmax(cw), redundant per-thread ----
    float swm[M_N];
    {
        float mx = cw[0];
#pragma unroll
        for (int m = 1; m < M_N; ++m) mx = fmaxf(mx, cw[m]);
        float s = 0.f;
#pragma unroll
        for (int m = 0; m < M_N; ++m) { swm[m] = expf(cw[m] - mx); s += swm[m]; }
        float inv = 1.f / s;
#pragma unroll
        for (int m = 0; m < M_N; ++m) swm[m] *= inv;
    }

    // ---- W1c into LDS ----
    if (tid < 128) {
#pragma unroll
        for (int h = 0; h < H_N; ++h) {
            float acc = 0.f;
#pragma unroll
            for (int m = 0; m < M_N; ++m)
                acc = fmaf(swm[m], w1[(m * H_N + h) * D_N + tid], acc);
            W1c[h][tid] = acc;
        }
    }
    asm volatile("s_waitcnt lgkmcnt(0)" ::: "memory");
    __builtin_amdgcn_s_barrier();

    // ---- Gram (16 threads, staggered) ----
    if (tid < 16) {
        const int i = tid >> 2, j = tid & 3;
        float s = 0.f;
        for (int st = 0; st < 128; ++st) {
            int dd = (st + tid * 8) & 127;
            s = fmaf(W1c[i][dd], W1c[j][dd], s);
        }
        Gsh[tid] = s;
    }
    asm volatile("s_waitcnt lgkmcnt(0)" ::: "memory");
    __builtin_amdgcn_s_barrier();

    // ---- thread 0: Jacobi + two-stage spectral scalars -> M2, M3 ----
    if (tid == 0) {
        float G[4][4], U[4][4];
#pragma unroll
        for (int i = 0; i < 4; ++i)
#pragma unroll
            for (int j = 0; j < 4; ++j) {
                G[i][j] = Gsh[i * 4 + j];
                U[i][j] = (i == j) ? 1.f : 0.f;
            }
        for (int sweep = 0; sweep < 6; ++sweep)
            for (int p = 0; p < 3; ++p)
                for (int q = p + 1; q < 4; ++q) {
                    float apq = G[p][q];
                    if (fabsf(apq) < 1e-30f) continue;
                    float theta = (G[q][q] - G[p][p]) / (2.f * apq);
                    float t = ((theta >= 0.f) ? 1.f : -1.f) /
                              (fabsf(theta) + sqrtf(theta * theta + 1.f));
                    float c = 1.f / sqrtf(t * t + 1.f), sn = t * c;
                    for (int i = 0; i < 4; ++i) {
                        float gip = G[i][p], giq = G[i][q];
                        G[i][p] = c * gip - sn * giq;
                        G[i][q] = sn * gip + c * giq;
                    }
                    for (int i = 0; i < 4; ++i) {
                        float gpi = G[p][i], gqi = G[q][i];
                        G[p][i] = c * gpi - sn * gqi;
                        G[q][i] = sn * gpi + c * gqi;
                    }
                    for (int i = 0; i < 4; ++i) {
                        float uip = U[i][p], uiq = U[i][q];
                        U[i][p] = c * uip - sn * uiq;
                        U[i][q] = sn * uip + c * uiq;
                    }
                }
        float lam[4];
#pragma unroll
        for (int i = 0; i < 4; ++i) lam[i] = G[i][i];
        int ord[4] = {0, 1, 2, 3};
        for (int i = 0; i < 4; ++i)
            for (int j = i + 1; j < 4; ++j)
                if (lam[ord[j]] > lam[ord[i]]) { int t2 = ord[i]; ord[i] = ord[j]; ord[j] = t2; }

        const float a = al[0], r = rs[0];
        float c1[4], S2a[4];
        for (int p = 0; p < 4; ++p) {
            int e = ord[p];
            float S = sqrtf(fmaxf(lam[e], 0.f));
            float x = ss[p];
            float sp = (x > 20.f) ? x : log1pf(expf(x));
            float ratio = (S > 1e-30f) ? ((sp * S + sh[p]) / S) : sp;
            c1[e] = a * ratio + r;
            S2a[e] = fabsf(c1[e]) * S;      // |singular values| of W2
        }
        int ord2[4] = {0, 1, 2, 3};
        for (int i = 0; i < 4; ++i)
            for (int j = i + 1; j < 4; ++j)
                if (S2a[ord2[j]] > S2a[ord2[i]]) { int t2 = ord2[i]; ord2[i] = ord2[j]; ord2[j] = t2; }
        float c12[4];
        for (int p = 0; p < 4; ++p) {
            int e = ord2[p];
            float Sa = S2a[e];
            float x = ss[p];
            float sp = (x > 20.f) ? x : log1pf(expf(x));
            float ratio2 = (Sa > 1e-30f) ? ((sp * Sa + sh[p]) / Sa) : sp;
            c12[e] = (a * ratio2 + r) * c1[e];
        }
#pragma unroll
        for (int i = 0; i < 4; ++i)
#pragma unroll
            for (int j = 0; j < 4; ++j) {
                float m2 = 0.f, m3 = 0.f;
#pragma unroll
                for (int e = 0; e < 4; ++e) {
                    float uu = U[i][e] * U[j][e];
                    m2 = fmaf(uu, c1[e], m2);
                    m3 = fmaf(uu, c12[e], m3);
                }
                Msh[i * 4 + j] = m2;
                Msh[16 + i * 4 + j] = m3;
            }
    }
    asm volatile("s_waitcnt lgkmcnt(0)" ::: "memory");
    __builtin_amdgcn_s_barrier();

    // ---- per-thread W2/W3 columns ----
    float w2v[H_N], w3v[H_N];
#pragma unroll
    for (int h = 0; h < H_N; ++h) {
        float s2 = 0.f, s3 = 0.f;
#pragma unroll
        for (int k4 = 0; k4 < 4; ++k4) {
            float wc = W1c[k4][d];
            s2 = fmaf(Msh[h * 4 + k4], wc, s2);
            s3 = fmaf(Msh[16 + h * 4 + k4], wc, s3);
        }
        w2v[h] = s2;
        w3v[h] = s3;
    }

    // thread computes row = lane of its wave's 64 rows
    const int rd_base = wv_id * WAVE_FLOATS + lane * HIST_N + (HIST_N - M_N);

    auto compute_tile = [&](int buf, size_t t) {
        const float* L = (const float*)&lds4[buf][0] + rd_base;
        float x0 = L[0];
        float h1[H_N];
#pragma unroll
        for (int h = 0; h < H_N; ++h) h1[h] = x0 * wv[0][h];
#pragma unroll
        for (int c = 0; c < 7; ++c) {
            float2 q = *(const float2*)(L + 1 + 2 * c);   // 8B-aligned
#pragma unroll
            for (int h = 0; h < H_N; ++h) h1[h] = fmaf(q.x, wv[1 + 2 * c][h], h1[h]);
#pragma unroll
            for (int h = 0; h < H_N; ++h) h1[h] = fmaf(q.y, wv[2 + 2 * c][h], h1[h]);
        }
        float acc = b3v;
#pragma unroll
        for (int h = 0; h < H_N; ++h) {
            float v = fmaxf(h1[h] + b1v[h], 0.f);
            float u = fmaxf(fmaf(v, w2v[h], b2v[h]), 0.f);
            acc = fmaf(u, w3v[h], acc);
        }
        out[t * TILE_ROWS + wv_id * 64 + lane] = acc;
    };

    // ---- main loop: wave-private, no barriers, counted vmcnt ----
    for (int k = 0; k < TPB; k += 2) {
        // tile k: set A -> buf0
        if (k == 0) asm volatile("s_waitcnt vmcnt(8)" ::: "memory");
        else        asm volatile("s_waitcnt vmcnt(9)" ::: "memory");
        WRITE_SET(a0, a1, a2, a3, a4, a5, a6, a7, 0);
        asm volatile("s_waitcnt lgkmcnt(0)" ::: "memory");
        compute_tile(0, tile0 + k);
        if (k + 2 < TPB) LOAD_SET(a0, a1, a2, a3, a4, a5, a6, a7, tile0 + k + 2);

        // tile k+1: set B -> buf1
        if (k + 1 == TPB - 1) asm volatile("s_waitcnt vmcnt(0)" ::: "memory");
        else                  asm volatile("s_waitcnt vmcnt(9)" ::: "memory");
        WRITE_SET(b0, b1r, b2r, b3r, b4, b5, b6, b7, 1);
        asm volatile("s_waitcnt lgkmcnt(0)" ::: "memory");
        compute_tile(1, tile0 + k + 1);
        if (k + 3 < TPB) LOAD_SET(b0, b1r, b2r, b3r, b4, b5, b6, b7, tile0 + k + 3);
    }
#undef LOAD_SET
#undef WRITE_SET
}

extern "C" void kernel_launch(void* const* d_in, const int* in_sizes, int n_in,
                              void* d_out, int out_size, void* d_ws, size_t ws_size,
                              hipStream_t stream) {
    const float* pa = (const float*)d_in[0];   // (B, D, HIST)
    const float* w1 = (const float*)d_in[1];   // (M, H, D)
    const float* b1 = (const float*)d_in[2];   // (1, H, D)
    const float* b2 = (const float*)d_in[3];   // (1, H, D)
    const float* b3 = (const float*)d_in[4];   // (1, D)
    const float* cw = (const float*)d_in[5];   // (M,)
    const float* ss = (const float*)d_in[6];   // (RANK,)
    const float* sh = (const float*)d_in[7];   // (RANK,)
    const float* al = (const float*)d_in[8];   // (1,)
    const float* rs = (const float*)d_in[9];   // (1,)
    float* out = (float*)d_out;                // (B, D) f32

    fused_kernel<<<NBLOCKS, NTHREADS, 0, stream>>>(pa, w1, b1, b2, b3, cw, ss, sh, al, rs, out);
}